// Round 1
// baseline (556.633 us; speedup 1.0000x reference)
//
#include <hip/hip_runtime.h>

// Dice metric: input (B=4, C=5, D=H=W=128) fp32, target (B,128^3) int.
// out[0] = mean over (B, classes 1..4) of (2*inter + eps)/(pred_c + tgt_c + eps)
// where pred = argmax_c input, counts binned per class.

static constexpr int   kB    = 4;
static constexpr int   kC    = 5;
static constexpr int   kN    = 128 * 128 * 128;   // 2,097,152 voxels per batch
static constexpr float kEPS  = 1e-5f;

// cnt layout: [b][group][class-1], group 0=pred,1=tgt,2=inter -> b*12 + g*4 + (c-1)
static constexpr int kNumCnt = kB * 3 * 4;        // 48 counters

__device__ __forceinline__ int argmax5(float v0, float v1, float v2, float v3, float v4) {
    int bi = 0; float bv = v0;
    if (v1 > bv) { bv = v1; bi = 1; }
    if (v2 > bv) { bv = v2; bi = 2; }
    if (v3 > bv) { bv = v3; bi = 3; }
    if (v4 > bv) { bv = v4; bi = 4; }
    return bi;   // first-max semantics, matches jnp.argmax
}

__device__ __forceinline__ void accum(int p, int t,
                                      unsigned* pc, unsigned* tc, unsigned* ic) {
#pragma unroll
    for (int c = 1; c < kC; ++c) {
        unsigned pm = (p == c) ? 1u : 0u;
        unsigned tm = (t == c) ? 1u : 0u;
        pc[c - 1] += pm;
        tc[c - 1] += tm;
        ic[c - 1] += pm & tm;
    }
}

__global__ __launch_bounds__(256) void dice_count_kernel(
        const float* __restrict__ in, const int* __restrict__ tgt,
        unsigned* __restrict__ cnt, int blocksPerB)
{
    const int b    = blockIdx.x / blocksPerB;
    const int blk  = blockIdx.x - b * blocksPerB;
    const float* inb = in  + (size_t)b * kC * kN;
    const int*   tb  = tgt + (size_t)b * kN;

    const int T    = blocksPerB * blockDim.x;        // threads per batch
    const int gtid = blk * blockDim.x + threadIdx.x;

    unsigned pc[4] = {0, 0, 0, 0};
    unsigned tc[4] = {0, 0, 0, 0};
    unsigned ic[4] = {0, 0, 0, 0};

    const float4* p0 = (const float4*)(inb + 0 * (size_t)kN);
    const float4* p1 = (const float4*)(inb + 1 * (size_t)kN);
    const float4* p2 = (const float4*)(inb + 2 * (size_t)kN);
    const float4* p3 = (const float4*)(inb + 3 * (size_t)kN);
    const float4* p4 = (const float4*)(inb + 4 * (size_t)kN);
    const int4*   pt = (const int4*)tb;

    const int nvec = kN / 4;                         // 524288 float4 groups
    for (int n4 = gtid; n4 < nvec; n4 += T) {
        float4 v0 = p0[n4];
        float4 v1 = p1[n4];
        float4 v2 = p2[n4];
        float4 v3 = p3[n4];
        float4 v4 = p4[n4];
        int4   t4 = pt[n4];

        accum(argmax5(v0.x, v1.x, v2.x, v3.x, v4.x), t4.x, pc, tc, ic);
        accum(argmax5(v0.y, v1.y, v2.y, v3.y, v4.y), t4.y, pc, tc, ic);
        accum(argmax5(v0.z, v1.z, v2.z, v3.z, v4.z), t4.z, pc, tc, ic);
        accum(argmax5(v0.w, v1.w, v2.w, v3.w, v4.w), t4.w, pc, tc, ic);
    }

    // Wave-64 butterfly reduction of the 12 counters
#pragma unroll
    for (int k = 0; k < 4; ++k) {
#pragma unroll
        for (int off = 32; off > 0; off >>= 1) {
            pc[k] += (unsigned)__shfl_down((int)pc[k], off, 64);
            tc[k] += (unsigned)__shfl_down((int)tc[k], off, 64);
            ic[k] += (unsigned)__shfl_down((int)ic[k], off, 64);
        }
    }

    if ((threadIdx.x & 63) == 0) {
        unsigned* base = cnt + b * 12;
#pragma unroll
        for (int k = 0; k < 4; ++k) {
            atomicAdd(&base[0 * 4 + k], pc[k]);
            atomicAdd(&base[1 * 4 + k], tc[k]);
            atomicAdd(&base[2 * 4 + k], ic[k]);
        }
    }
}

__global__ void dice_final_kernel(const unsigned* __restrict__ cnt,
                                  float* __restrict__ out)
{
    if (threadIdx.x == 0 && blockIdx.x == 0) {
        float s = 0.0f;
#pragma unroll
        for (int b = 0; b < kB; ++b) {
#pragma unroll
            for (int k = 0; k < 4; ++k) {
                float pr = (float)cnt[b * 12 + 0 * 4 + k];
                float tg = (float)cnt[b * 12 + 1 * 4 + k];
                float it = (float)cnt[b * 12 + 2 * 4 + k];
                s += (2.0f * it + kEPS) / (pr + tg + kEPS);
            }
        }
        out[0] = s * (1.0f / 16.0f);
    }
}

extern "C" void kernel_launch(void* const* d_in, const int* in_sizes, int n_in,
                              void* d_out, int out_size, void* d_ws, size_t ws_size,
                              hipStream_t stream) {
    const float* in  = (const float*)d_in[0];
    const int*   tgt = (const int*)d_in[1];
    float*       out = (float*)d_out;
    unsigned*    cnt = (unsigned*)d_ws;

    // Workspace is re-poisoned to 0xAA before every launch -> zero the counters.
    hipMemsetAsync(cnt, 0, kNumCnt * sizeof(unsigned), stream);

    const int blocksPerB = 256;   // 1024 blocks total, 4 per CU
    dice_count_kernel<<<dim3(kB * blocksPerB), dim3(256), 0, stream>>>(
        in, tgt, cnt, blocksPerB);
    dice_final_kernel<<<1, 64, 0, stream>>>(cnt, out);
}

// Round 2
// 259.182 us; speedup vs baseline: 2.1477x; 2.1477x over previous
//
#include <hip/hip_runtime.h>

// Dice metric: input (B=4, C=5, D=H=W=128) fp32, target (B,128^3) int32.
// out[0] = mean over (B, classes 1..4) of (2*inter + eps)/(pred_c + tgt_c + eps)
// where pred = argmax_c input.

static constexpr int   kB   = 4;
static constexpr int   kC   = 5;
static constexpr int   kN   = 128 * 128 * 128;      // voxels per batch
static constexpr float kEPS = 1e-5f;

static constexpr int TPB = 256;                     // threads per block
static constexpr int VPT = 4;                       // float4 groups per thread
static constexpr int GPB = TPB * VPT;               // 1024 float4 groups / block
static constexpr int BLOCKS_PER_BATCH = (kN / 4) / GPB;   // 512
static constexpr int kNumCnt = kB * 12;             // [b][group(P,T,I)][class-1]

__device__ __forceinline__ int argmax5(float v0, float v1, float v2, float v3, float v4) {
    int bi = 0; float bv = v0;
    if (v1 > bv) { bv = v1; bi = 1; }
    if (v2 > bv) { bv = v2; bi = 2; }
    if (v3 > bv) { bv = v3; bi = 3; }
    if (v4 > bv) { bv = v4; bi = 4; }
    return bi;   // first-max semantics == jnp.argmax
}

// Byte-packed counters: byte k of pack = count for class k+1. Max 16 voxels/thread.
__device__ __forceinline__ void acc1(int p, int t,
                                     unsigned& P, unsigned& T, unsigned& I) {
    unsigned pm = p ? (1u << ((p - 1) << 3)) : 0u;
    unsigned tm = t ? (1u << ((t - 1) << 3)) : 0u;
    P += pm;
    T += tm;
    I += (p == t) ? pm : 0u;      // p==t==0 -> pm==0, background excluded for free
}

__global__ __launch_bounds__(TPB) void dice_count_kernel(
        const float* __restrict__ in, const int* __restrict__ tgt,
        unsigned* __restrict__ cnt)
{
    const int b   = blockIdx.x >> 9;        // / BLOCKS_PER_BATCH (512)
    const int blk = blockIdx.x & 511;
    const float* inb = in  + (size_t)b * kC * kN;
    const int*   tb  = tgt + (size_t)b * kN;

    const float4* c0 = (const float4*)(inb + 0 * (size_t)kN);
    const float4* c1 = (const float4*)(inb + 1 * (size_t)kN);
    const float4* c2 = (const float4*)(inb + 2 * (size_t)kN);
    const float4* c3 = (const float4*)(inb + 3 * (size_t)kN);
    const float4* c4 = (const float4*)(inb + 4 * (size_t)kN);
    const int4*   tp = (const int4*)tb;

    const int base = blk * GPB + threadIdx.x;

    // Load everything first (independent registers -> max loads in flight).
    float4 v[VPT][5];
    int4   tv[VPT];
#pragma unroll
    for (int i = 0; i < VPT; ++i) {
        const int n4 = base + i * TPB;
        v[i][0] = c0[n4];
        v[i][1] = c1[n4];
        v[i][2] = c2[n4];
        v[i][3] = c3[n4];
        v[i][4] = c4[n4];
        tv[i]   = tp[n4];
    }

    unsigned P = 0, T = 0, I = 0;
#pragma unroll
    for (int i = 0; i < VPT; ++i) {
        acc1(argmax5(v[i][0].x, v[i][1].x, v[i][2].x, v[i][3].x, v[i][4].x), tv[i].x, P, T, I);
        acc1(argmax5(v[i][0].y, v[i][1].y, v[i][2].y, v[i][3].y, v[i][4].y), tv[i].y, P, T, I);
        acc1(argmax5(v[i][0].z, v[i][1].z, v[i][2].z, v[i][3].z, v[i][4].z), tv[i].z, P, T, I);
        acc1(argmax5(v[i][0].w, v[i][1].w, v[i][2].w, v[i][3].w, v[i][4].w), tv[i].w, P, T, I);
    }

    // Widen bytes -> halfwords so a 64-lane sum can't overflow (16*64=1024 < 65536).
    // r[2g+0]: classes 1(lo16) & 3(hi16); r[2g+1]: classes 2(lo16) & 4(hi16).
    unsigned r[6];
    r[0] = P & 0x00FF00FFu;  r[1] = (P >> 8) & 0x00FF00FFu;
    r[2] = T & 0x00FF00FFu;  r[3] = (T >> 8) & 0x00FF00FFu;
    r[4] = I & 0x00FF00FFu;  r[5] = (I >> 8) & 0x00FF00FFu;

#pragma unroll
    for (int k = 0; k < 6; ++k) {
#pragma unroll
        for (int off = 32; off > 0; off >>= 1) {
            r[k] += (unsigned)__shfl_down((int)r[k], off, 64);
        }
    }

    __shared__ unsigned sred[4][6];         // 4 waves per block
    const int wave = threadIdx.x >> 6;
    if ((threadIdx.x & 63) == 0) {
#pragma unroll
        for (int k = 0; k < 6; ++k) sred[wave][k] = r[k];
    }
    __syncthreads();

    // One thread per packed pair -> 12 atomicAdds per block total.
    if (threadIdx.x < 6) {
        const int j = threadIdx.x;
        unsigned s = sred[0][j] + sred[1][j] + sred[2][j] + sred[3][j];  // <= 4096/field
        const int g    = j >> 1;            // 0=pred,1=tgt,2=inter
        const int kLo  = j & 1;             // class-1 index: 0 or 1
        unsigned* dst = cnt + b * 12 + g * 4;
        atomicAdd(&dst[kLo],     s & 0xFFFFu);
        atomicAdd(&dst[kLo + 2], s >> 16);
    }
}

__global__ void dice_final_kernel(const unsigned* __restrict__ cnt,
                                  float* __restrict__ out)
{
    if (threadIdx.x == 0 && blockIdx.x == 0) {
        float s = 0.0f;
#pragma unroll
        for (int b = 0; b < kB; ++b) {
#pragma unroll
            for (int k = 0; k < 4; ++k) {
                float pr = (float)cnt[b * 12 + 0 * 4 + k];
                float tg = (float)cnt[b * 12 + 1 * 4 + k];
                float it = (float)cnt[b * 12 + 2 * 4 + k];
                s += (2.0f * it + kEPS) / (pr + tg + kEPS);
            }
        }
        out[0] = s * (1.0f / 16.0f);
    }
}

extern "C" void kernel_launch(void* const* d_in, const int* in_sizes, int n_in,
                              void* d_out, int out_size, void* d_ws, size_t ws_size,
                              hipStream_t stream) {
    const float* in  = (const float*)d_in[0];
    const int*   tgt = (const int*)d_in[1];
    float*       out = (float*)d_out;
    unsigned*    cnt = (unsigned*)d_ws;

    // d_ws is poisoned to 0xAA before every launch -> zero the counters.
    hipMemsetAsync(cnt, 0, kNumCnt * sizeof(unsigned), stream);

    dice_count_kernel<<<dim3(kB * BLOCKS_PER_BATCH), dim3(TPB), 0, stream>>>(in, tgt, cnt);
    dice_final_kernel<<<1, 64, 0, stream>>>(cnt, out);
}